// Round 4
// baseline (28.358 us; speedup 1.0000x reference)
//
#include <hip/hip_runtime.h>

#define NTIMES 8
#define NFREQS 64
#define NSRC   512
#define NBL    66
#define C_MPS  299792458.0f

// Output: harness holds Re(vis): [2][2][66][8][64] float32 (135168 elems).
__global__ __launch_bounds__(64) void rime_kernel(
    const float* __restrict__ sky,       // [2][2][64][512]
    const float* __restrict__ beam,      // [2][2][8][64][512]
    const float* __restrict__ antpos,    // [12][3]
    const float* __restrict__ svec,      // [8][3][512]
    const float* __restrict__ freqs,     // [64]
    const int*   __restrict__ ant2model, // [12]
    const int*   __restrict__ bls,       // [66][2]
    float*       __restrict__ out,
    int out_n)
{
    const int b = blockIdx.x;
    const int f = b & (NFREQS - 1);
    const int t = (b >> 6) & (NTIMES - 1);
    const int k = b >> 9;

    const int a1 = bls[2 * k + 0];
    const int a2 = bls[2 * k + 1];
    const int m1 = ant2model[a1];
    const int m2 = ant2model[a2];
    const float bx = antpos[3 * a2 + 0] - antpos[3 * a1 + 0];
    const float by = antpos[3 * a2 + 1] - antpos[3 * a1 + 1];
    const float bz = antpos[3 * a2 + 2] - antpos[3 * a1 + 2];
    // phase in REVOLUTIONS: rev = -f/c * (blvec . svec); v_cos takes revolutions
    const float coefrev = -freqs[f] / C_MPS;

    const int lane = threadIdx.x; // 0..63

    const float4* sv4  = (const float4*)(svec + (size_t)t * 3 * NSRC);           // [3][128] f4
    const float4* b1p0 = (const float4*)(beam + ((size_t)m1 * NTIMES + t) * NFREQS * NSRC
                                              + (size_t)f * NSRC);
    const float4* b1p1 = b1p0 + (size_t)(2 * NTIMES * NFREQS * NSRC) / 4;        // p-stride
    const float4* b2p0 = (const float4*)(beam + ((size_t)m2 * NTIMES + t) * NFREQS * NSRC
                                              + (size_t)f * NSRC);
    const float4* b2p1 = b2p0 + (size_t)(2 * NTIMES * NFREQS * NSRC) / 4;
    const float4* sk   = (const float4*)(sky + (size_t)f * NSRC);                // pq stride 8192 f4

    float a00 = 0.f, a01 = 0.f, a10 = 0.f, a11 = 0.f;

#pragma unroll
    for (int it = 0; it < 2; ++it) {
        const int s4 = lane + it * 64; // float4 index, 0..127
        const float4 vx   = sv4[s4];
        const float4 vy   = sv4[128 + s4];
        const float4 vz   = sv4[256 + s4];
        const float4 vb10 = b1p0[s4];
        const float4 vb11 = b1p1[s4];
        const float4 vb20 = b2p0[s4];
        const float4 vb21 = b2p1[s4];
        const float4 v00  = sk[s4];
        const float4 v01  = sk[ 8192 + s4];
        const float4 v10  = sk[16384 + s4];
        const float4 v11  = sk[24576 + s4];

#define RIME_BODY(CX)                                                              \
        {                                                                          \
            const float rev = __builtin_amdgcn_fractf(                             \
                coefrev * (bx * vx.CX + by * vy.CX + bz * vz.CX));                 \
            const float cs = __builtin_amdgcn_cosf(rev);                           \
            a00 += vb10.CX * vb20.CX * v00.CX * cs;                                \
            a01 += vb10.CX * vb21.CX * v01.CX * cs;                                \
            a10 += vb11.CX * vb20.CX * v10.CX * cs;                                \
            a11 += vb11.CX * vb21.CX * v11.CX * cs;                                \
        }
        RIME_BODY(x)
        RIME_BODY(y)
        RIME_BODY(z)
        RIME_BODY(w)
#undef RIME_BODY
    }

    // Butterfly (xor) reduction: every lane ends with the FULL 64-lane sum.
    float vals[4] = { a00, a01, a10, a11 };
#pragma unroll
    for (int i = 0; i < 4; ++i) {
        float v = vals[i];
#pragma unroll
        for (int off = 32; off > 0; off >>= 1)
            v += __shfl_xor(v, off, 64);
        vals[i] = v;
    }

    if (lane < 4) {
        const int pq = lane; // p = pq>>1, q = pq&1
        const int idx = pq * (NBL * NTIMES * NFREQS) + ((k * NTIMES + t) * NFREQS + f);
        if (idx < out_n) out[idx] = vals[pq];
    }
}

extern "C" void kernel_launch(void* const* d_in, const int* in_sizes, int n_in,
                              void* d_out, int out_size, void* d_ws, size_t ws_size,
                              hipStream_t stream) {
    const float* sky     = (const float*)d_in[0];
    const float* beam    = (const float*)d_in[1];
    const float* antpos  = (const float*)d_in[2];
    const float* svec    = (const float*)d_in[3];
    const float* freqs   = (const float*)d_in[4];
    const int*   ant2mod = (const int*)d_in[5];
    const int*   bls     = (const int*)d_in[6];
    float*       out     = (float*)d_out;

    const int nblocks = NBL * NTIMES * NFREQS; // 33792
    rime_kernel<<<nblocks, 64, 0, stream>>>(sky, beam, antpos, svec, freqs,
                                            ant2mod, bls, out, out_size);
}

// Round 5
// 20.182 us; speedup vs baseline: 1.4051x; 1.4051x over previous
//
#include <hip/hip_runtime.h>

#define NTIMES 8
#define NFREQS 64
#define NSRC   512
#define NBL    66
#define C_MPS  299792458.0f

// Output: Re(vis): [2][2][66][8][64] float32 (135168 elems).
// One block per (t,f): phase 1 builds the 16 baseline-invariant weight vectors
// w[m1m2][pq][s] in LDS; phase 2 sweeps baselines reading weights from LDS.
__global__ __launch_bounds__(512) void rime_kernel(
    const float* __restrict__ sky,       // [2][2][64][512]
    const float* __restrict__ beam,      // [2][2][8][64][512]
    const float* __restrict__ antpos,    // [12][3]
    const float* __restrict__ svec,      // [8][3][512]
    const float* __restrict__ freqs,     // [64]
    const int*   __restrict__ ant2model, // [12]
    const int*   __restrict__ bls,       // [66][2]
    float*       __restrict__ out,
    int out_n)
{
    __shared__ float wsm[16 * NSRC]; // [c=(m1*2+m2)][pq][s], 32 KB

    const int bid = blockIdx.x;
    const int f = bid & (NFREQS - 1);
    const int t = bid >> 6;

    const int tid  = threadIdx.x; // 0..511
    const int lane = tid & 63;
    const int wv   = tid >> 6;    // 0..7

    // ---- Phase 1: thread == source; build 16 weight vectors in LDS ----
    {
        const int s = tid;
        const size_t beam_tf = (size_t)t * NFREQS * NSRC + (size_t)f * NSRC + s;
        float bv[2][2]; // [p][m]
        bv[0][0] = beam[(size_t)0 * NTIMES * NFREQS * NSRC + beam_tf];
        bv[0][1] = beam[(size_t)1 * NTIMES * NFREQS * NSRC + beam_tf];
        bv[1][0] = beam[(size_t)2 * NTIMES * NFREQS * NSRC + beam_tf];
        bv[1][1] = beam[(size_t)3 * NTIMES * NFREQS * NSRC + beam_tf];
        const size_t sky_f = (size_t)f * NSRC + s;
        float skv[4];
        skv[0] = sky[(size_t)0 * NFREQS * NSRC + sky_f];
        skv[1] = sky[(size_t)1 * NFREQS * NSRC + sky_f];
        skv[2] = sky[(size_t)2 * NFREQS * NSRC + sky_f];
        skv[3] = sky[(size_t)3 * NFREQS * NSRC + sky_f];
#pragma unroll
        for (int m1 = 0; m1 < 2; ++m1)
#pragma unroll
            for (int m2 = 0; m2 < 2; ++m2)
#pragma unroll
                for (int pq = 0; pq < 4; ++pq) {
                    const int p = pq >> 1, q = pq & 1;
                    wsm[((m1 * 2 + m2) * 4 + pq) * NSRC + s] =
                        bv[p][m1] * skv[pq] * bv[q][m2];
                }
    }

    // per-lane svec registers (baseline-invariant): sources s = 4*(lane+64*it)..+3
    const float4* sv4 = (const float4*)(svec + (size_t)t * 3 * NSRC);
    float4 vx[2], vy[2], vz[2];
#pragma unroll
    for (int it = 0; it < 2; ++it) {
        vx[it] = sv4[lane + 64 * it];
        vy[it] = sv4[128 + lane + 64 * it];
        vz[it] = sv4[256 + lane + 64 * it];
    }

    // phase in REVOLUTIONS for v_cos: rev = -f/c * (blvec . svec)
    const float coefrev = -freqs[f] / C_MPS;

    __syncthreads();

    // ---- Phase 2: wave wv sweeps baselines k = wv, wv+8, ... ----
    for (int k = wv; k < NBL; k += 8) {
        const int a1 = bls[2 * k + 0];
        const int a2 = bls[2 * k + 1];
        const int c  = ant2model[a1] * 2 + ant2model[a2];
        const float bx = antpos[3 * a2 + 0] - antpos[3 * a1 + 0];
        const float by = antpos[3 * a2 + 1] - antpos[3 * a1 + 1];
        const float bz = antpos[3 * a2 + 2] - antpos[3 * a1 + 2];
        const float4* wp = (const float4*)(wsm + (size_t)c * 4 * NSRC);

        float a00 = 0.f, a01 = 0.f, a10 = 0.f, a11 = 0.f;
#pragma unroll
        for (int it = 0; it < 2; ++it) {
            const int s4 = lane + 64 * it;
            const float4 w00 = wp[s4];          // pq stride = 512/4 = 128 float4
            const float4 w01 = wp[128 + s4];
            const float4 w10 = wp[256 + s4];
            const float4 w11 = wp[384 + s4];

#define RIME_BODY(CX)                                                          \
            {                                                                  \
                const float rev = __builtin_amdgcn_fractf(                     \
                    coefrev * (bx * vx[it].CX + by * vy[it].CX + bz * vz[it].CX)); \
                const float cs = __builtin_amdgcn_cosf(rev);                   \
                a00 += w00.CX * cs;                                            \
                a01 += w01.CX * cs;                                            \
                a10 += w10.CX * cs;                                            \
                a11 += w11.CX * cs;                                            \
            }
            RIME_BODY(x)
            RIME_BODY(y)
            RIME_BODY(z)
            RIME_BODY(w)
#undef RIME_BODY
        }

        // Butterfly: every lane ends with the full 64-lane sum.
        float vals[4] = { a00, a01, a10, a11 };
#pragma unroll
        for (int i = 0; i < 4; ++i) {
            float v = vals[i];
#pragma unroll
            for (int off = 32; off > 0; off >>= 1)
                v += __shfl_xor(v, off, 64);
            vals[i] = v;
        }

        if (lane < 4) {
            float v = vals[0];
            if (lane == 1) v = vals[1];
            else if (lane == 2) v = vals[2];
            else if (lane == 3) v = vals[3];
            const int idx = lane * (NBL * NTIMES * NFREQS)
                          + k * (NTIMES * NFREQS) + t * NFREQS + f;
            if (idx < out_n) out[idx] = v;
        }
    }
}

extern "C" void kernel_launch(void* const* d_in, const int* in_sizes, int n_in,
                              void* d_out, int out_size, void* d_ws, size_t ws_size,
                              hipStream_t stream) {
    const float* sky     = (const float*)d_in[0];
    const float* beam    = (const float*)d_in[1];
    const float* antpos  = (const float*)d_in[2];
    const float* svec    = (const float*)d_in[3];
    const float* freqs   = (const float*)d_in[4];
    const int*   ant2mod = (const int*)d_in[5];
    const int*   bls     = (const int*)d_in[6];
    float*       out     = (float*)d_out;

    const int nblocks = NTIMES * NFREQS; // 512, one per (t,f)
    rime_kernel<<<nblocks, 512, 0, stream>>>(sky, beam, antpos, svec, freqs,
                                             ant2mod, bls, out, out_size);
}

// Round 7
// 17.589 us; speedup vs baseline: 1.6123x; 1.1474x over previous
//
#include <hip/hip_runtime.h>

#define NTIMES 8
#define NFREQS 64
#define NSRC   512
#define NBL    66
#define C_MPS  299792458.0f

// DPP-based wave64 reduction (VALU-only, no LDS). Full sum lands in lane 63.
template <int CTRL, int ROW_MASK>
__device__ __forceinline__ float dpp_add(float v) {
    const int moved = __builtin_amdgcn_update_dpp(
        0, __builtin_bit_cast(int, v), CTRL, ROW_MASK, 0xf, true);
    return v + __builtin_bit_cast(float, moved);
}
__device__ __forceinline__ float wave_sum_lane63(float v) {
    v = dpp_add<0x111, 0xf>(v); // row_shr:1
    v = dpp_add<0x112, 0xf>(v); // row_shr:2
    v = dpp_add<0x114, 0xf>(v); // row_shr:4
    v = dpp_add<0x118, 0xf>(v); // row_shr:8  -> lane15 of each row = row sum
    v = dpp_add<0x142, 0xa>(v); // row_bcast:15 into rows 1,3
    v = dpp_add<0x143, 0xc>(v); // row_bcast:31 into rows 2,3 -> lane63 = total
    return v;
}

// Output: Re(vis): [2][2][66][8][64] float32 (135168 elems).
__global__ __launch_bounds__(512) void rime_kernel(
    const float* __restrict__ sky,       // [2][2][64][512]
    const float* __restrict__ beam,      // [2][2][8][64][512]
    const float* __restrict__ antpos,    // [12][3]
    const float* __restrict__ svec,      // [8][3][512]
    const float* __restrict__ freqs,     // [64]
    const int*   __restrict__ ant2model, // [12]
    const int*   __restrict__ bls,       // [66][2]
    float*       __restrict__ out,
    int out_n)
{
    __shared__ float wsm[16 * NSRC]; // [c=(m1*2+m2)][pq][s], 32 KB

    const int bid = blockIdx.x;
    const int f = bid & (NFREQS - 1);
    const int t = bid >> 6;

    const int tid  = threadIdx.x; // 0..511
    const int lane = tid & 63;
    const int wv   = tid >> 6;    // 0..7

    // ---- Phase 1: thread == source; build 16 weight vectors in LDS ----
    {
        const int s = tid;
        const size_t beam_tf = (size_t)t * NFREQS * NSRC + (size_t)f * NSRC + s;
        float bv[2][2]; // [p][m]
        bv[0][0] = beam[(size_t)0 * NTIMES * NFREQS * NSRC + beam_tf];
        bv[0][1] = beam[(size_t)1 * NTIMES * NFREQS * NSRC + beam_tf];
        bv[1][0] = beam[(size_t)2 * NTIMES * NFREQS * NSRC + beam_tf];
        bv[1][1] = beam[(size_t)3 * NTIMES * NFREQS * NSRC + beam_tf];
        const size_t sky_f = (size_t)f * NSRC + s;
        float skv[4];
        skv[0] = sky[(size_t)0 * NFREQS * NSRC + sky_f];
        skv[1] = sky[(size_t)1 * NFREQS * NSRC + sky_f];
        skv[2] = sky[(size_t)2 * NFREQS * NSRC + sky_f];
        skv[3] = sky[(size_t)3 * NFREQS * NSRC + sky_f];
#pragma unroll
        for (int m1 = 0; m1 < 2; ++m1)
#pragma unroll
            for (int m2 = 0; m2 < 2; ++m2)
#pragma unroll
                for (int pq = 0; pq < 4; ++pq) {
                    const int p = pq >> 1, q = pq & 1;
                    wsm[((m1 * 2 + m2) * 4 + pq) * NSRC + s] =
                        bv[p][m1] * skv[pq] * bv[q][m2];
                }
    }

    // per-lane svec registers (baseline-invariant)
    const float4* sv4 = (const float4*)(svec + (size_t)t * 3 * NSRC);
    float4 vx[2], vy[2], vz[2];
#pragma unroll
    for (int it = 0; it < 2; ++it) {
        vx[it] = sv4[lane + 64 * it];
        vy[it] = sv4[128 + lane + 64 * it];
        vz[it] = sv4[256 + lane + 64 * it];
    }

    // phase in REVOLUTIONS for v_cos: rev = -f/c * (blvec . svec)
    const float coefrev = -freqs[f] / C_MPS;

    __syncthreads();

    // ---- Phase 2: wave wv sweeps baselines k = wv, wv+8, ... ----
    for (int k = wv; k < NBL; k += 8) {
        const int a1 = bls[2 * k + 0];
        const int a2 = bls[2 * k + 1];
        const int c  = ant2model[a1] * 2 + ant2model[a2];
        const float bx = antpos[3 * a2 + 0] - antpos[3 * a1 + 0];
        const float by = antpos[3 * a2 + 1] - antpos[3 * a1 + 1];
        const float bz = antpos[3 * a2 + 2] - antpos[3 * a1 + 2];
        const float4* wp = (const float4*)(wsm + (size_t)c * 4 * NSRC);

        float a00 = 0.f, a01 = 0.f, a10 = 0.f, a11 = 0.f;
#pragma unroll
        for (int it = 0; it < 2; ++it) {
            const int s4 = lane + 64 * it;
            const float4 w00 = wp[s4];          // pq stride = 512/4 = 128 float4
            const float4 w01 = wp[128 + s4];
            const float4 w10 = wp[256 + s4];
            const float4 w11 = wp[384 + s4];

#define RIME_BODY(CX)                                                          \
            {                                                                  \
                const float rev = __builtin_amdgcn_fractf(                     \
                    coefrev * (bx * vx[it].CX + by * vy[it].CX + bz * vz[it].CX)); \
                const float cs = __builtin_amdgcn_cosf(rev);                   \
                a00 += w00.CX * cs;                                            \
                a01 += w01.CX * cs;                                            \
                a10 += w10.CX * cs;                                            \
                a11 += w11.CX * cs;                                            \
            }
            RIME_BODY(x)
            RIME_BODY(y)
            RIME_BODY(z)
            RIME_BODY(w)
#undef RIME_BODY
        }

        // VALU (DPP) reduction: full sums in lane 63, no LDS traffic.
        const float s00 = wave_sum_lane63(a00);
        const float s01 = wave_sum_lane63(a01);
        const float s10 = wave_sum_lane63(a10);
        const float s11 = wave_sum_lane63(a11);

        if (lane == 63) {
            const int base = k * (NTIMES * NFREQS) + t * NFREQS + f;
            const int pqs  = NBL * NTIMES * NFREQS; // 33792
            if (base + 3 * pqs < out_n) {
                out[base]           = s00;
                out[base + pqs]     = s01;
                out[base + 2 * pqs] = s10;
                out[base + 3 * pqs] = s11;
            }
        }
    }
}

extern "C" void kernel_launch(void* const* d_in, const int* in_sizes, int n_in,
                              void* d_out, int out_size, void* d_ws, size_t ws_size,
                              hipStream_t stream) {
    const float* sky     = (const float*)d_in[0];
    const float* beam    = (const float*)d_in[1];
    const float* antpos  = (const float*)d_in[2];
    const float* svec    = (const float*)d_in[3];
    const float* freqs   = (const float*)d_in[4];
    const int*   ant2mod = (const int*)d_in[5];
    const int*   bls     = (const int*)d_in[6];
    float*       out     = (float*)d_out;

    const int nblocks = NTIMES * NFREQS; // 512, one per (t,f)
    rime_kernel<<<nblocks, 512, 0, stream>>>(sky, beam, antpos, svec, freqs,
                                             ant2mod, bls, out, out_size);
}

// Round 8
// 16.722 us; speedup vs baseline: 1.6959x; 1.0519x over previous
//
#include <hip/hip_runtime.h>

#define NTIMES 8
#define NFREQS 64
#define NSRC   512
#define NBL    66
#define KHALF  33
#define C_MPS  299792458.0f

// DPP-based wave64 reduction (VALU-only, no LDS). Full sum lands in lane 63.
template <int CTRL, int ROW_MASK>
__device__ __forceinline__ float dpp_add(float v) {
    const int moved = __builtin_amdgcn_update_dpp(
        0, __builtin_bit_cast(int, v), CTRL, ROW_MASK, 0xf, true);
    return v + __builtin_bit_cast(float, moved);
}
__device__ __forceinline__ float wave_sum_lane63(float v) {
    v = dpp_add<0x111, 0xf>(v); // row_shr:1
    v = dpp_add<0x112, 0xf>(v); // row_shr:2
    v = dpp_add<0x114, 0xf>(v); // row_shr:4
    v = dpp_add<0x118, 0xf>(v); // row_shr:8  -> lane15 of each row = row sum
    v = dpp_add<0x142, 0xa>(v); // row_bcast:15 into rows 1,3
    v = dpp_add<0x143, 0xc>(v); // row_bcast:31 into rows 2,3 -> lane63 = total
    return v;
}

// Output: Re(vis): [2][2][66][8][64] float32 (135168 elems).
// Block = (t, f, khalf): phase 1 builds 16 weight vectors in LDS,
// phase 2's 8 waves sweep 33 baselines.
__global__ __launch_bounds__(512) void rime_kernel(
    const float* __restrict__ sky,       // [2][2][64][512]
    const float* __restrict__ beam,      // [2][2][8][64][512]
    const float* __restrict__ antpos,    // [12][3]
    const float* __restrict__ svec,      // [8][3][512]
    const float* __restrict__ freqs,     // [64]
    const int*   __restrict__ ant2model, // [12]
    const int*   __restrict__ bls,       // [66][2]
    float*       __restrict__ out,
    int out_n)
{
    __shared__ float wsm[16 * NSRC]; // [c=(m1*2+m2)][pq][s], 32 KB

    const int bid = blockIdx.x;
    const int f  = bid & (NFREQS - 1);
    const int t  = (bid >> 6) & (NTIMES - 1);
    const int kh = bid >> 9; // 0 or 1

    const int tid  = threadIdx.x; // 0..511
    const int lane = tid & 63;
    const int wv   = tid >> 6;    // 0..7

    // ---- Phase 1: thread == source; build 16 weight vectors in LDS ----
    {
        const int s = tid;
        const size_t beam_tf = (size_t)t * NFREQS * NSRC + (size_t)f * NSRC + s;
        float bv[2][2]; // [p][m]
        bv[0][0] = beam[(size_t)0 * NTIMES * NFREQS * NSRC + beam_tf];
        bv[0][1] = beam[(size_t)1 * NTIMES * NFREQS * NSRC + beam_tf];
        bv[1][0] = beam[(size_t)2 * NTIMES * NFREQS * NSRC + beam_tf];
        bv[1][1] = beam[(size_t)3 * NTIMES * NFREQS * NSRC + beam_tf];
        const size_t sky_f = (size_t)f * NSRC + s;
        float skv[4];
        skv[0] = sky[(size_t)0 * NFREQS * NSRC + sky_f];
        skv[1] = sky[(size_t)1 * NFREQS * NSRC + sky_f];
        skv[2] = sky[(size_t)2 * NFREQS * NSRC + sky_f];
        skv[3] = sky[(size_t)3 * NFREQS * NSRC + sky_f];
#pragma unroll
        for (int m1 = 0; m1 < 2; ++m1)
#pragma unroll
            for (int m2 = 0; m2 < 2; ++m2)
#pragma unroll
                for (int pq = 0; pq < 4; ++pq) {
                    const int p = pq >> 1, q = pq & 1;
                    wsm[((m1 * 2 + m2) * 4 + pq) * NSRC + s] =
                        bv[p][m1] * skv[pq] * bv[q][m2];
                }
    }

    // per-lane svec registers (baseline-invariant)
    const float4* sv4 = (const float4*)(svec + (size_t)t * 3 * NSRC);
    float4 vx[2], vy[2], vz[2];
#pragma unroll
    for (int it = 0; it < 2; ++it) {
        vx[it] = sv4[lane + 64 * it];
        vy[it] = sv4[128 + lane + 64 * it];
        vz[it] = sv4[256 + lane + 64 * it];
    }

    // phase in REVOLUTIONS for v_cos: rev = (-f/c) * (blvec . svec)
    const float coefrev = -freqs[f] / C_MPS;

    __syncthreads();

    // ---- Phase 2: wave wv sweeps kk = wv, wv+8, ... within this half ----
    for (int kk = wv; kk < KHALF; kk += 8) {
        const int k  = kh * KHALF + kk;
        const int a1 = bls[2 * k + 0];
        const int a2 = bls[2 * k + 1];
        const int c  = ant2model[a1] * 2 + ant2model[a2];
        // pre-scaled baseline vector: rev = bxc*sx + byc*sy + bzc*sz
        const float bxc = coefrev * (antpos[3 * a2 + 0] - antpos[3 * a1 + 0]);
        const float byc = coefrev * (antpos[3 * a2 + 1] - antpos[3 * a1 + 1]);
        const float bzc = coefrev * (antpos[3 * a2 + 2] - antpos[3 * a1 + 2]);
        const float4* wp = (const float4*)(wsm + (size_t)c * 4 * NSRC);

        float a00 = 0.f, a01 = 0.f, a10 = 0.f, a11 = 0.f;
#pragma unroll
        for (int it = 0; it < 2; ++it) {
            const int s4 = lane + 64 * it;
            const float4 w00 = wp[s4];          // pq stride = 512/4 = 128 float4
            const float4 w01 = wp[128 + s4];
            const float4 w10 = wp[256 + s4];
            const float4 w11 = wp[384 + s4];

#define RIME_BODY(CX)                                                          \
            {                                                                  \
                const float rev = __builtin_amdgcn_fractf(                     \
                    bxc * vx[it].CX + byc * vy[it].CX + bzc * vz[it].CX);      \
                const float cs = __builtin_amdgcn_cosf(rev);                   \
                a00 += w00.CX * cs;                                            \
                a01 += w01.CX * cs;                                            \
                a10 += w10.CX * cs;                                            \
                a11 += w11.CX * cs;                                            \
            }
            RIME_BODY(x)
            RIME_BODY(y)
            RIME_BODY(z)
            RIME_BODY(w)
#undef RIME_BODY
        }

        // VALU (DPP) reduction: full sums in lane 63, no LDS traffic.
        const float s00 = wave_sum_lane63(a00);
        const float s01 = wave_sum_lane63(a01);
        const float s10 = wave_sum_lane63(a10);
        const float s11 = wave_sum_lane63(a11);

        if (lane == 63) {
            const int base = k * (NTIMES * NFREQS) + t * NFREQS + f;
            const int pqs  = NBL * NTIMES * NFREQS; // 33792
            if (base + 3 * pqs < out_n) {
                out[base]           = s00;
                out[base + pqs]     = s01;
                out[base + 2 * pqs] = s10;
                out[base + 3 * pqs] = s11;
            }
        }
    }
}

extern "C" void kernel_launch(void* const* d_in, const int* in_sizes, int n_in,
                              void* d_out, int out_size, void* d_ws, size_t ws_size,
                              hipStream_t stream) {
    const float* sky     = (const float*)d_in[0];
    const float* beam    = (const float*)d_in[1];
    const float* antpos  = (const float*)d_in[2];
    const float* svec    = (const float*)d_in[3];
    const float* freqs   = (const float*)d_in[4];
    const int*   ant2mod = (const int*)d_in[5];
    const int*   bls     = (const int*)d_in[6];
    float*       out     = (float*)d_out;

    const int nblocks = NTIMES * NFREQS * 2; // 1024: (t, f, khalf)
    rime_kernel<<<nblocks, 512, 0, stream>>>(sky, beam, antpos, svec, freqs,
                                             ant2mod, bls, out, out_size);
}

// Round 9
// 15.286 us; speedup vs baseline: 1.8552x; 1.0939x over previous
//
#include <hip/hip_runtime.h>

#define NTIMES 8
#define NFREQS 64
#define NSRC   512
#define NBL    66
#define KHALF  33
#define C_MPS  299792458.0f

// DPP-based wave64 reduction (VALU-only, no LDS). Full sum lands in lane 63.
template <int CTRL, int ROW_MASK>
__device__ __forceinline__ float dpp_add(float v) {
    const int moved = __builtin_amdgcn_update_dpp(
        0, __builtin_bit_cast(int, v), CTRL, ROW_MASK, 0xf, true);
    return v + __builtin_bit_cast(float, moved);
}
__device__ __forceinline__ float wave_sum_lane63(float v) {
    v = dpp_add<0x111, 0xf>(v); // row_shr:1
    v = dpp_add<0x112, 0xf>(v); // row_shr:2
    v = dpp_add<0x114, 0xf>(v); // row_shr:4
    v = dpp_add<0x118, 0xf>(v); // row_shr:8  -> lane15 of each row = row sum
    v = dpp_add<0x142, 0xa>(v); // row_bcast:15 into rows 1,3
    v = dpp_add<0x143, 0xc>(v); // row_bcast:31 into rows 2,3 -> lane63 = total
    return v;
}

// Output: Re(vis): [2][2][66][8][64] float32 (135168 elems).
// Block = (t, f, khalf). Phase 1: 16 weight vectors + baseline metadata in LDS.
// Phase 2: 8 waves sweep 33 baselines, fully unrolled, metadata from LDS.
__global__ __launch_bounds__(512) void rime_kernel(
    const float* __restrict__ sky,       // [2][2][64][512]
    const float* __restrict__ beam,      // [2][2][8][64][512]
    const float* __restrict__ antpos,    // [12][3]
    const float* __restrict__ svec,      // [8][3][512]
    const float* __restrict__ freqs,     // [64]
    const int*   __restrict__ ant2model, // [12]
    const int*   __restrict__ bls,       // [66][2]
    float*       __restrict__ out)
{
    __shared__ float  wsm[16 * NSRC]; // [c][pq][s], 32 KB
    __shared__ float4 btab[NBL];      // (blvec.xyz, bitcast class), 1 KB

    const int bid = blockIdx.x;
    const int f  = bid & (NFREQS - 1);
    const int t  = (bid >> 6) & (NTIMES - 1);
    const int kh = bid >> 9; // 0 or 1

    const int tid  = threadIdx.x; // 0..511
    const int lane = tid & 63;
    const int wv   = tid >> 6;    // 0..7

    // ---- Phase 1a: baseline metadata table (threads 0..65) ----
    if (tid < NBL) {
        const int a1 = bls[2 * tid + 0];
        const int a2 = bls[2 * tid + 1];
        float4 e;
        e.x = antpos[3 * a2 + 0] - antpos[3 * a1 + 0];
        e.y = antpos[3 * a2 + 1] - antpos[3 * a1 + 1];
        e.z = antpos[3 * a2 + 2] - antpos[3 * a1 + 2];
        e.w = __builtin_bit_cast(float, ant2model[a1] * 2 + ant2model[a2]);
        btab[tid] = e;
    }

    // ---- Phase 1b: thread == source; build 16 weight vectors in LDS ----
    {
        const int s = tid;
        const size_t beam_tf = (size_t)t * NFREQS * NSRC + (size_t)f * NSRC + s;
        float bv[2][2]; // [p][m]
        bv[0][0] = beam[(size_t)0 * NTIMES * NFREQS * NSRC + beam_tf];
        bv[0][1] = beam[(size_t)1 * NTIMES * NFREQS * NSRC + beam_tf];
        bv[1][0] = beam[(size_t)2 * NTIMES * NFREQS * NSRC + beam_tf];
        bv[1][1] = beam[(size_t)3 * NTIMES * NFREQS * NSRC + beam_tf];
        const size_t sky_f = (size_t)f * NSRC + s;
        float skv[4];
        skv[0] = sky[(size_t)0 * NFREQS * NSRC + sky_f];
        skv[1] = sky[(size_t)1 * NFREQS * NSRC + sky_f];
        skv[2] = sky[(size_t)2 * NFREQS * NSRC + sky_f];
        skv[3] = sky[(size_t)3 * NFREQS * NSRC + sky_f];
#pragma unroll
        for (int m1 = 0; m1 < 2; ++m1)
#pragma unroll
            for (int m2 = 0; m2 < 2; ++m2)
#pragma unroll
                for (int pq = 0; pq < 4; ++pq) {
                    const int p = pq >> 1, q = pq & 1;
                    wsm[((m1 * 2 + m2) * 4 + pq) * NSRC + s] =
                        bv[p][m1] * skv[pq] * bv[q][m2];
                }
    }

    // per-lane svec registers (baseline-invariant)
    const float4* sv4 = (const float4*)(svec + (size_t)t * 3 * NSRC);
    float4 vx[2], vy[2], vz[2];
#pragma unroll
    for (int it = 0; it < 2; ++it) {
        vx[it] = sv4[lane + 64 * it];
        vy[it] = sv4[128 + lane + 64 * it];
        vz[it] = sv4[256 + lane + 64 * it];
    }

    // phase in REVOLUTIONS for v_cos: rev = (-f/c) * (blvec . svec)
    const float coefrev = -freqs[f] / C_MPS;

    __syncthreads();

    // ---- Phase 2: wave wv handles kk = wv + 8*i, i = 0..4 (unrolled) ----
#pragma unroll
    for (int i = 0; i < 5; ++i) {
        const int kk = wv + 8 * i;
        if (kk < KHALF) {
            const int k = kh * KHALF + kk;
            const float4 m = btab[k];
            const int   c   = __builtin_bit_cast(int, m.w);
            const float bxc = coefrev * m.x;
            const float byc = coefrev * m.y;
            const float bzc = coefrev * m.z;
            const float4* wp = (const float4*)(wsm + (size_t)c * 4 * NSRC);

            float a00 = 0.f, a01 = 0.f, a10 = 0.f, a11 = 0.f;
#pragma unroll
            for (int it = 0; it < 2; ++it) {
                const int s4 = lane + 64 * it;
                const float4 w00 = wp[s4];          // pq stride = 128 float4
                const float4 w01 = wp[128 + s4];
                const float4 w10 = wp[256 + s4];
                const float4 w11 = wp[384 + s4];

#define RIME_BODY(CX)                                                          \
                {                                                              \
                    const float rev = __builtin_amdgcn_fractf(                 \
                        bxc * vx[it].CX + byc * vy[it].CX + bzc * vz[it].CX);  \
                    const float cs = __builtin_amdgcn_cosf(rev);               \
                    a00 += w00.CX * cs;                                        \
                    a01 += w01.CX * cs;                                        \
                    a10 += w10.CX * cs;                                        \
                    a11 += w11.CX * cs;                                        \
                }
                RIME_BODY(x)
                RIME_BODY(y)
                RIME_BODY(z)
                RIME_BODY(w)
#undef RIME_BODY
            }

            const float s00 = wave_sum_lane63(a00);
            const float s01 = wave_sum_lane63(a01);
            const float s10 = wave_sum_lane63(a10);
            const float s11 = wave_sum_lane63(a11);

            if (lane == 63) {
                const int base = k * (NTIMES * NFREQS) + t * NFREQS + f;
                const int pqs  = NBL * NTIMES * NFREQS; // 33792
                out[base]           = s00;
                out[base + pqs]     = s01;
                out[base + 2 * pqs] = s10;
                out[base + 3 * pqs] = s11;
            }
        }
    }
}

extern "C" void kernel_launch(void* const* d_in, const int* in_sizes, int n_in,
                              void* d_out, int out_size, void* d_ws, size_t ws_size,
                              hipStream_t stream) {
    const float* sky     = (const float*)d_in[0];
    const float* beam    = (const float*)d_in[1];
    const float* antpos  = (const float*)d_in[2];
    const float* svec    = (const float*)d_in[3];
    const float* freqs   = (const float*)d_in[4];
    const int*   ant2mod = (const int*)d_in[5];
    const int*   bls     = (const int*)d_in[6];
    float*       out     = (float*)d_out;

    const int nblocks = NTIMES * NFREQS * 2; // 1024: (t, f, khalf)
    rime_kernel<<<nblocks, 512, 0, stream>>>(sky, beam, antpos, svec, freqs,
                                             ant2mod, bls, out);
}